// Round 1
// baseline (706.683 us; speedup 1.0000x reference)
//
#include <hip/hip_runtime.h>
#include <math.h>

#define NB   4
#define NN   4096
#define FIN  128
#define FOUT 128   // H*U
#define NH   4
#define UU   32

typedef short bf16x8 __attribute__((ext_vector_type(8)));
typedef float f32x4  __attribute__((ext_vector_type(4)));

__device__ __forceinline__ unsigned short f2bf(float v) {
    unsigned int u = __float_as_uint(v);
    unsigned int r = u + 0x7fffu + ((u >> 16) & 1u);   // RNE
    return (unsigned short)(r >> 16);
}
__device__ __forceinline__ float bf2f(unsigned short s) {
    return __uint_as_float(((unsigned int)s) << 16);
}

// ---------------- Kernel 1: h = x@W (fp32); emit h as bf16 hi/lo transposed
// [b][128u][4096j], plus f1 ([row][h]) and f2T ([b][h][j]) ----------------
#define K1_ROWS 64
#define K1_RT   8
#define K1_CT   4
#define XPAD    132

__global__ __launch_bounds__(256) void k1_feat(
    const float* __restrict__ x, const float* __restrict__ W,
    const float* __restrict__ a_src, const float* __restrict__ a_dst,
    unsigned short* __restrict__ hhi, unsigned short* __restrict__ hlo,
    float* __restrict__ f1g, float* __restrict__ f2T)
{
    __shared__ __align__(16) float Wq[32 * FOUT];
    __shared__ __align__(16) float xs[K1_ROWS * XPAD];

    const int tid  = threadIdx.x;
    const int row0 = blockIdx.x * K1_ROWS;

    const float4* x4 = (const float4*)(x + (size_t)row0 * FIN);
    for (int idx = tid; idx < K1_ROWS * FIN / 4; idx += 256) {
        int r = idx >> 5, q = idx & 31;
        *(float4*)(xs + r * XPAD + q * 4) = x4[idx];
    }

    const int cg = tid & 31;
    const int rg = tid >> 5;
    float acc[K1_RT][K1_CT];
    #pragma unroll
    for (int rr = 0; rr < K1_RT; rr++)
        #pragma unroll
        for (int cc = 0; cc < K1_CT; cc++) acc[rr][cc] = 0.f;

    for (int kt = 0; kt < 4; kt++) {
        __syncthreads();
        for (int idx = tid; idx < 32 * FOUT / 4; idx += 256)
            ((float4*)Wq)[idx] = ((const float4*)W)[kt * 1024 + idx];
        __syncthreads();
        #pragma unroll
        for (int k4 = 0; k4 < 8; k4++) {
            const int kb = kt * 32 + k4 * 4;
            float4 xv[K1_RT];
            #pragma unroll
            for (int rr = 0; rr < K1_RT; rr++)
                xv[rr] = *(const float4*)(xs + (rg * K1_RT + rr) * XPAD + kb);
            #pragma unroll
            for (int kk = 0; kk < 4; kk++) {
                float wv[K1_CT];
                #pragma unroll
                for (int cc = 0; cc < K1_CT; cc++)
                    wv[cc] = Wq[(k4 * 4 + kk) * FOUT + cg + 32 * cc];
                #pragma unroll
                for (int rr = 0; rr < K1_RT; rr++) {
                    float xk = ((const float*)&xv[rr])[kk];
                    #pragma unroll
                    for (int cc = 0; cc < K1_CT; cc++)
                        acc[rr][cc] = fmaf(xk, wv[cc], acc[rr][cc]);
                }
            }
        }
    }
    __syncthreads();
    #pragma unroll
    for (int rr = 0; rr < K1_RT; rr++)
        #pragma unroll
        for (int cc = 0; cc < K1_CT; cc++)
            xs[(rg * K1_RT + rr) * XPAD + cg + 32 * cc] = acc[rr][cc];
    __syncthreads();

    const int bb = row0 >> 12;
    const int ib = row0 & (NN - 1);

    // transposed bf16 hi/lo write: hhi/hlo[(b*128 + col)*4096 + i]
    for (int idx = tid; idx < FOUT * K1_ROWS; idx += 256) {
        int col = idx >> 6;          // 0..127
        int r   = idx & 63;
        float v = xs[r * XPAD + col];
        unsigned short hb = f2bf(v);
        unsigned short lb = f2bf(v - bf2f(hb));
        size_t o = ((size_t)bb * FOUT + col) * NN + (size_t)(ib + r);
        hhi[o] = hb;
        hlo[o] = lb;
    }

    for (int task = tid; task < K1_ROWS * NH * 2; task += 256) {
        int row = task >> 3;
        int head = (task >> 1) & 3;
        int which = task & 1;
        const float* av = which ? a_dst : a_src;
        float s = 0.f;
        #pragma unroll
        for (int u = 0; u < UU; u++)
            s += xs[row * XPAD + head * UU + u] * av[head * UU + u];
        if (which) f2T[((size_t)bb * NH + head) * NN + (size_t)(ib + row)] = s;
        else       f1g[(size_t)(row0 + row) * NH + head] = s;
    }
}

// ---------------- Kernel 2: fused dense flash-GAT ----------------
// 512 blocks x 512 threads. Wave w: head = w&3, i-sub = (w&4)?16:0.
// Per wave: A-frag = P[16i x 32j] built in-register in MFMA A layout
// (row = lane&15, k = (lane>>4)*8 + e), B-frags from hhi/hlo transposed
// layout (8 contiguous j bf16 = one dwordx4). Online softmax, m_run init 0,
// defer-max THR=8. Split-bf16 PV (3 MFMA products) keeps fp32-level accuracy.
// No LDS, no barriers.
__global__ __launch_bounds__(512, 4) void k2_flash(
    const float* __restrict__ adj,
    const unsigned short* __restrict__ hhi,
    const unsigned short* __restrict__ hlo,
    const float* __restrict__ f1g,
    const float* __restrict__ f2T,
    const float* __restrict__ bias,
    float* __restrict__ out)
{
    const int blk  = blockIdx.x;
    const int xcd  = blk & 7;                 // round-robin XCD assignment
    const int b    = xcd >> 1;                // one batch per XCD pair -> L2-resident h
    const int itile = (blk >> 3) | ((xcd & 1) << 6);   // 0..127
    const int i0   = itile << 5;              // 32-row tile
    const int tid  = threadIdx.x;
    const int lane = tid & 63;
    const int w    = tid >> 6;                // 0..7
    const int h    = w & 3;
    const int isub = (w & 4) << 2;            // 0 or 16
    const int r16  = lane & 15;               // A row / B col / C col
    const int ksl  = lane >> 4;               // j-slice 0..3

    const int irow = i0 + isub + r16;                      // this lane's score row i
    const size_t grow = (size_t)b * NN + irow;

    const float* adjp = adj + grow * NN + ksl * 8;
    const float* f2p  = f2T + ((size_t)b * NH + h) * NN + ksl * 8;
    const float  f1i  = f1g[grow * NH + h];
    const int    uc   = h * UU + r16;
    const unsigned short* ph0 = hhi + ((size_t)b * FOUT + uc) * NN + ksl * 8;
    const unsigned short* ph1 = ph0 + (size_t)16 * NN;
    const unsigned short* pl0 = hlo + ((size_t)b * FOUT + uc) * NN + ksl * 8;
    const unsigned short* pl1 = pl0 + (size_t)16 * NN;

    f32x4 c0 = {0.f, 0.f, 0.f, 0.f};
    f32x4 c1 = {0.f, 0.f, 0.f, 0.f};
    float m_run = 0.f;        // shift-invariant: 0-init avoids -inf garbage tiles
    float l_run = 0.f;        // per-lane partial (this lane's 8-j slices)
    const int sbase = ksl << 2;

    for (int jb = 0; jb < NN; jb += 32) {
        float4 a0  = *(const float4*)(adjp + jb);
        float4 a1  = *(const float4*)(adjp + jb + 4);
        float4 f20 = *(const float4*)(f2p + jb);
        float4 f21 = *(const float4*)(f2p + jb + 4);
        bf16x8 bh0 = *(const bf16x8*)(ph0 + jb);
        bf16x8 bh1 = *(const bf16x8*)(ph1 + jb);
        bf16x8 bl0 = *(const bf16x8*)(pl0 + jb);
        bf16x8 bl1 = *(const bf16x8*)(pl1 + jb);

        const int jdiff = irow - jb - ksl * 8;   // self-loop position, if in [0,8)
        float s[8];
        {
            const float* av = (const float*)&a0;
            const float* fv = (const float*)&f20;
            #pragma unroll
            for (int e = 0; e < 4; e++) {
                float t = f1i + fv[e];
                t = fmaxf(t, 0.2f * t);                       // LeakyReLU(0.2)
                s[e] = ((av[e] > 0.f) | (e == jdiff)) ? t : -1e9f;
            }
            const float* av2 = (const float*)&a1;
            const float* fv2 = (const float*)&f21;
            #pragma unroll
            for (int e = 0; e < 4; e++) {
                float t = f1i + fv2[e];
                t = fmaxf(t, 0.2f * t);
                s[e + 4] = ((av2[e] > 0.f) | ((e + 4) == jdiff)) ? t : -1e9f;
            }
        }

        float mt = fmaxf(fmaxf(fmaxf(s[0], s[1]), fmaxf(s[2], s[3])),
                         fmaxf(fmaxf(s[4], s[5]), fmaxf(s[6], s[7])));
        mt = fmaxf(mt, __shfl_xor(mt, 16, 64));
        mt = fmaxf(mt, __shfl_xor(mt, 32, 64));   // full-row tile max (4 copies)

        if (!__all(mt <= m_run + 8.f)) {          // defer-max (T13), wave-uniform
            float m_new = fmaxf(m_run, mt);
            float sc = __expf(m_run - m_new);     // ==1 for rows not growing
            m_run = m_new;
            l_run *= sc;
            #pragma unroll
            for (int rg = 0; rg < 4; rg++) {      // C rows = ksl*4+rg; scale lives in lane r
                float scr = __shfl(sc, sbase + rg, 64);
                c0[rg] *= scr;
                c1[rg] *= scr;
            }
        }

        float p[8];
        float lsum = 0.f;
        #pragma unroll
        for (int e = 0; e < 8; e++) {
            p[e] = __expf(s[e] - m_run);          // masked -> exp(-1e9) = 0
            lsum += p[e];
        }
        l_run += lsum;

        bf16x8 pa, pb;
        #pragma unroll
        for (int e = 0; e < 8; e++) {
            unsigned short hb = f2bf(p[e]);
            pa[e] = (short)hb;
            pb[e] = (short)f2bf(p[e] - bf2f(hb)); // p_lo
        }

        // (pa+pb)*(bh+bl) ~ pa*bh + pb*bh + pa*bl   (pb*bl ~ 2^-16, dropped)
        c0 = __builtin_amdgcn_mfma_f32_16x16x32_bf16(pa, bh0, c0, 0, 0, 0);
        c1 = __builtin_amdgcn_mfma_f32_16x16x32_bf16(pa, bh1, c1, 0, 0, 0);
        c0 = __builtin_amdgcn_mfma_f32_16x16x32_bf16(pb, bh0, c0, 0, 0, 0);
        c1 = __builtin_amdgcn_mfma_f32_16x16x32_bf16(pb, bh1, c1, 0, 0, 0);
        c0 = __builtin_amdgcn_mfma_f32_16x16x32_bf16(pa, bl0, c0, 0, 0, 0);
        c1 = __builtin_amdgcn_mfma_f32_16x16x32_bf16(pa, bl1, c1, 0, 0, 0);
    }

    // reduce l across the 4 j-slice copies (every lane ends with its row's l)
    float l = l_run;
    l += __shfl_xor(l, 16, 64);
    l += __shfl_xor(l, 32, 64);
    const float inv = 1.f / l;                    // self-loop guarantees l > 0

    const float bias0 = bias[h * UU + r16];
    const float bias1 = bias[h * UU + 16 + r16];
    #pragma unroll
    for (int rg = 0; rg < 4; rg++) {
        float invr = __shfl(inv, sbase + rg, 64); // inv_l for C row ksl*4+rg
        int r = isub + sbase + rg;
        size_t orow = ((size_t)b * NN + (size_t)(i0 + r)) * FOUT;
        float o0 = c0[rg] * invr + bias0;
        o0 = o0 > 0.f ? o0 : expm1f(o0);          // ELU
        out[orow + h * UU + r16] = o0;
        float o1 = c1[rg] * invr + bias1;
        o1 = o1 > 0.f ? o1 : expm1f(o1);
        out[orow + h * UU + 16 + r16] = o1;
    }
}

extern "C" void kernel_launch(void* const* d_in, const int* in_sizes, int n_in,
                              void* d_out, int out_size, void* d_ws, size_t ws_size,
                              hipStream_t stream) {
    const float* x     = (const float*)d_in[0];
    const float* adj   = (const float*)d_in[1];
    const float* W     = (const float*)d_in[2];
    const float* a_src = (const float*)d_in[3];
    const float* a_dst = (const float*)d_in[4];
    const float* bias  = (const float*)d_in[5];
    float* out = (float*)d_out;

    unsigned short* hhi = (unsigned short*)d_ws;                   // 4 MB
    unsigned short* hlo = hhi + (size_t)NB * FOUT * NN;            // 4 MB
    float* f1g = (float*)(hlo + (size_t)NB * FOUT * NN);           // 256 KB
    float* f2T = f1g + (size_t)NB * NN * NH;                       // 256 KB

    k1_feat<<<NB * NN / K1_ROWS, 256, 0, stream>>>(x, W, a_src, a_dst, hhi, hlo, f1g, f2T);
    k2_flash<<<512, 512, 0, stream>>>(adj, hhi, hlo, f1g, f2T, bias, out);
}

// Round 3
// 599.065 us; speedup vs baseline: 1.1796x; 1.1796x over previous
//
#include <hip/hip_runtime.h>
#include <math.h>

#define NB   4
#define NN   4096
#define FIN  128
#define FOUT 128   // H*U
#define NH   4
#define UU   32

typedef short bf16x8 __attribute__((ext_vector_type(8)));
typedef float f32x4  __attribute__((ext_vector_type(4)));

__device__ __forceinline__ unsigned short f2bf(float v) {
    unsigned int u = __float_as_uint(v);
    unsigned int r = u + 0x7fffu + ((u >> 16) & 1u);   // RNE
    return (unsigned short)(r >> 16);
}
__device__ __forceinline__ float bf2f(unsigned short s) {
    return __uint_as_float(((unsigned int)s) << 16);
}

// ---------------- Kernel 1: h = x@W (fp32); emit h as bf16 hi/lo transposed
// [b][128u][4096j] (16B packed stores), plus f1 ([row][h]) and f2T ([b][h][j]) ---
#define K1_ROWS 64
#define K1_RT   8
#define K1_CT   4
#define XPAD    132

__global__ __launch_bounds__(256) void k1_feat(
    const float* __restrict__ x, const float* __restrict__ W,
    const float* __restrict__ a_src, const float* __restrict__ a_dst,
    unsigned short* __restrict__ hhi, unsigned short* __restrict__ hlo,
    float* __restrict__ f1g, float* __restrict__ f2T)
{
    __shared__ __align__(16) float Wq[32 * FOUT];
    __shared__ __align__(16) float xs[K1_ROWS * XPAD];

    const int tid  = threadIdx.x;
    const int row0 = blockIdx.x * K1_ROWS;

    const float4* x4 = (const float4*)(x + (size_t)row0 * FIN);
    for (int idx = tid; idx < K1_ROWS * FIN / 4; idx += 256) {
        int r = idx >> 5, q = idx & 31;
        *(float4*)(xs + r * XPAD + q * 4) = x4[idx];
    }

    const int cg = tid & 31;
    const int rg = tid >> 5;
    float acc[K1_RT][K1_CT];
    #pragma unroll
    for (int rr = 0; rr < K1_RT; rr++)
        #pragma unroll
        for (int cc = 0; cc < K1_CT; cc++) acc[rr][cc] = 0.f;

    for (int kt = 0; kt < 4; kt++) {
        __syncthreads();
        for (int idx = tid; idx < 32 * FOUT / 4; idx += 256)
            ((float4*)Wq)[idx] = ((const float4*)W)[kt * 1024 + idx];
        __syncthreads();
        #pragma unroll
        for (int k4 = 0; k4 < 8; k4++) {
            const int kb = kt * 32 + k4 * 4;
            float4 xv[K1_RT];
            #pragma unroll
            for (int rr = 0; rr < K1_RT; rr++)
                xv[rr] = *(const float4*)(xs + (rg * K1_RT + rr) * XPAD + kb);
            #pragma unroll
            for (int kk = 0; kk < 4; kk++) {
                float wv[K1_CT];
                #pragma unroll
                for (int cc = 0; cc < K1_CT; cc++)
                    wv[cc] = Wq[(k4 * 4 + kk) * FOUT + cg + 32 * cc];
                #pragma unroll
                for (int rr = 0; rr < K1_RT; rr++) {
                    float xk = ((const float*)&xv[rr])[kk];
                    #pragma unroll
                    for (int cc = 0; cc < K1_CT; cc++)
                        acc[rr][cc] = fmaf(xk, wv[cc], acc[rr][cc]);
                }
            }
        }
    }
    __syncthreads();
    #pragma unroll
    for (int rr = 0; rr < K1_RT; rr++)
        #pragma unroll
        for (int cc = 0; cc < K1_CT; cc++)
            xs[(rg * K1_RT + rr) * XPAD + cg + 32 * cc] = acc[rr][cc];
    __syncthreads();

    const int bb = row0 >> 12;
    const int ib = row0 & (NN - 1);

    // transposed bf16 hi/lo, 8 i-values packed per 16B store
    for (int t = tid; t < FOUT * (K1_ROWS / 8); t += 256) {   // 1024 tasks
        const int i8  = t & 7;
        const int col = t >> 3;
        unsigned hh[8], ll[8];
        #pragma unroll
        for (int k = 0; k < 8; k++) {
            float v = xs[(i8 * 8 + k) * XPAD + col];
            unsigned u = __float_as_uint(v);
            unsigned r = (u + 0x7fffu + ((u >> 16) & 1u)) & 0xffff0000u;
            hh[k] = r >> 16;
            float lo = v - __uint_as_float(r);
            ll[k] = __float_as_uint(lo) >> 16;       // trunc: pa*bl term corrects it
        }
        uint4 hv, lv;
        hv.x = hh[0] | (hh[1] << 16); hv.y = hh[2] | (hh[3] << 16);
        hv.z = hh[4] | (hh[5] << 16); hv.w = hh[6] | (hh[7] << 16);
        lv.x = ll[0] | (ll[1] << 16); lv.y = ll[2] | (ll[3] << 16);
        lv.z = ll[4] | (ll[5] << 16); lv.w = ll[6] | (ll[7] << 16);
        size_t o = ((size_t)bb * FOUT + col) * NN + (size_t)(ib + i8 * 8);
        *(uint4*)(hhi + o) = hv;
        *(uint4*)(hlo + o) = lv;
    }

    for (int task = tid; task < K1_ROWS * NH * 2; task += 256) {
        int row = task >> 3;
        int head = (task >> 1) & 3;
        int which = task & 1;
        const float* av = which ? a_dst : a_src;
        float s = 0.f;
        #pragma unroll
        for (int u = 0; u < UU; u++)
            s += xs[row * XPAD + head * UU + u] * av[head * UU + u];
        if (which) f2T[((size_t)bb * NH + head) * NN + (size_t)(ib + row)] = s;
        else       f1g[(size_t)(row0 + row) * NH + head] = s;
    }
}

// ---------------- Kernel 2: fused dense flash-GAT, LDS-staged adj/f2 ----------------
// 512 blocks x 512 threads. Wave w: head = w&3, i-sub = (w&4)?16:0.
// adj[32x64] + f2[4x64] staged cooperatively (coalesced 256B segments),
// double-buffered, ONE barrier per 64-j step. Scores read via conflict-free
// ds_read_b128 (pad 68 -> 2-way, free per m136). h (bf16 hi/lo, transposed)
// read from global (L2-resident, b pinned per XCD pair) with one-half-ahead
// register prefetch. Online softmax (m_run=0 init, defer-max THR=8),
// split-bf16 PV (3 products).
__global__ __launch_bounds__(512, 4) void k2_flash(
    const float* __restrict__ adj,
    const unsigned short* __restrict__ hhi,
    const unsigned short* __restrict__ hlo,
    const float* __restrict__ f1g,
    const float* __restrict__ f2T,
    const float* __restrict__ bias,
    float* __restrict__ out)
{
    __shared__ __align__(16) float adjS[2][32][68];
    __shared__ __align__(16) float f2S[2][NH][64];

    const int blk  = blockIdx.x;
    const int xcd  = blk & 7;
    const int b    = xcd >> 1;                          // batch pinned per XCD pair
    const int itile = (blk >> 3) | ((xcd & 1) << 6);    // 0..127
    const int i0   = itile << 5;
    const int tid  = threadIdx.x;
    const int lane = tid & 63;
    const int w    = tid >> 6;
    const int h    = w & 3;
    const int isub = (w & 4) << 2;                      // 0 or 16
    const int r16  = lane & 15;
    const int ksl  = lane >> 4;                         // j-slice 0..3

    const int irow = i0 + isub + r16;
    const size_t grow = (size_t)b * NN + irow;

    // staging assignment (coalesced: 16 lanes x 16B = 256B per row segment)
    const int srow = tid >> 4;                          // 0..31
    const int scol = (tid & 15) << 2;                   // 0..60
    const float* aglb = adj + ((size_t)b * NN + i0 + srow) * NN + scol;
    const float* fglb = f2T + ((size_t)b * NH + (srow & 3)) * NN + scol; // tid<64 only

    const float  f1i  = f1g[grow * NH + h];
    const int    uc   = h * UU + r16;
    const unsigned short* ph0 = hhi + ((size_t)b * FOUT + uc) * NN + ksl * 8;
    const unsigned short* ph1 = ph0 + (size_t)16 * NN;
    const unsigned short* pl0 = hlo + ((size_t)b * FOUT + uc) * NN + ksl * 8;
    const unsigned short* pl1 = pl0 + (size_t)16 * NN;

    f32x4 c0 = {0.f, 0.f, 0.f, 0.f};
    f32x4 c1 = {0.f, 0.f, 0.f, 0.f};
    float m_run = 0.f;
    float l_run = 0.f;
    const int sbase = ksl << 2;

    auto CHUNK = [&](int buf, int co, int jg,
                     bf16x8 BH0, bf16x8 BH1, bf16x8 BL0, bf16x8 BL1) {
        const int cb = co + (ksl << 3);
        float4 a0  = *(const float4*)&adjS[buf][isub + r16][cb];
        float4 a1  = *(const float4*)&adjS[buf][isub + r16][cb + 4];
        float4 f20 = *(const float4*)&f2S[buf][h][cb];
        float4 f21 = *(const float4*)&f2S[buf][h][cb + 4];
        const int jdiff = irow - (jg + (ksl << 3));

        float s[8];
        {
            const float* av = (const float*)&a0;
            const float* fv = (const float*)&f20;
            #pragma unroll
            for (int e = 0; e < 4; e++) {
                float t = f1i + fv[e];
                t = fmaxf(t, 0.2f * t);                       // LeakyReLU(0.2)
                s[e] = ((av[e] > 0.f) | (e == jdiff)) ? t : -1e9f;
            }
            const float* av2 = (const float*)&a1;
            const float* fv2 = (const float*)&f21;
            #pragma unroll
            for (int e = 0; e < 4; e++) {
                float t = f1i + fv2[e];
                t = fmaxf(t, 0.2f * t);
                s[e + 4] = ((av2[e] > 0.f) | ((e + 4) == jdiff)) ? t : -1e9f;
            }
        }

        float mt = fmaxf(fmaxf(fmaxf(s[0], s[1]), fmaxf(s[2], s[3])),
                         fmaxf(fmaxf(s[4], s[5]), fmaxf(s[6], s[7])));
        mt = fmaxf(mt, __shfl_xor(mt, 16, 64));
        mt = fmaxf(mt, __shfl_xor(mt, 32, 64));

        if (!__all(mt <= m_run + 8.f)) {                  // defer-max (rare)
            float m_new = fmaxf(m_run, mt);
            float sc = __expf(m_run - m_new);
            m_run = m_new;
            l_run *= sc;
            #pragma unroll
            for (int rg = 0; rg < 4; rg++) {
                float scr = __shfl(sc, sbase + rg, 64);
                c0[rg] *= scr;
                c1[rg] *= scr;
            }
        }

        float p[8];
        float lsum = 0.f;
        #pragma unroll
        for (int e = 0; e < 8; e++) {
            p[e] = __expf(s[e] - m_run);
            lsum += p[e];
        }
        l_run += lsum;

        bf16x8 pa, pb;
        #pragma unroll
        for (int e = 0; e < 8; e++) {
            unsigned u = __float_as_uint(p[e]);
            unsigned short hi = (unsigned short)(u >> 16);    // trunc hi
            float plo = p[e] - __uint_as_float(u & 0xffff0000u);
            pa[e] = (short)hi;
            pb[e] = (short)(__float_as_uint(plo) >> 16);      // trunc lo (exact enough)
        }

        c0 = __builtin_amdgcn_mfma_f32_16x16x32_bf16(pa, BH0, c0, 0, 0, 0);
        c1 = __builtin_amdgcn_mfma_f32_16x16x32_bf16(pa, BH1, c1, 0, 0, 0);
        c0 = __builtin_amdgcn_mfma_f32_16x16x32_bf16(pb, BH0, c0, 0, 0, 0);
        c1 = __builtin_amdgcn_mfma_f32_16x16x32_bf16(pb, BH1, c1, 0, 0, 0);
        c0 = __builtin_amdgcn_mfma_f32_16x16x32_bf16(pa, BL0, c0, 0, 0, 0);
        c1 = __builtin_amdgcn_mfma_f32_16x16x32_bf16(pa, BL1, c1, 0, 0, 0);
    };

    // ---- prologue: stage jb=0, load h half0
    {
        float4 av = *(const float4*)(aglb);
        *(float4*)&adjS[0][srow][scol] = av;
        if (tid < 64) {
            float4 fv = *(const float4*)(fglb);
            *(float4*)&f2S[0][srow & 3][scol] = fv;
        }
    }
    bf16x8 BH0c = *(const bf16x8*)(ph0);
    bf16x8 BH1c = *(const bf16x8*)(ph1);
    bf16x8 BL0c = *(const bf16x8*)(pl0);
    bf16x8 BL1c = *(const bf16x8*)(pl1);
    __syncthreads();

    for (int jb = 0; jb < NN; jb += 64) {
        const int buf = (jb >> 6) & 1;
        const bool more = (jb + 64) < NN;
        float4 aNxt, fNxt;
        if (more) {
            aNxt = *(const float4*)(aglb + jb + 64);
            if (tid < 64) fNxt = *(const float4*)(fglb + jb + 64);
        }
        // h regs for half1 of this step
        bf16x8 BH0n = *(const bf16x8*)(ph0 + jb + 32);
        bf16x8 BH1n = *(const bf16x8*)(ph1 + jb + 32);
        bf16x8 BL0n = *(const bf16x8*)(pl0 + jb + 32);
        bf16x8 BL1n = *(const bf16x8*)(pl1 + jb + 32);

        CHUNK(buf, 0, jb, BH0c, BH1c, BL0c, BL1c);

        if (more) {                                        // h half0 of next step
            BH0c = *(const bf16x8*)(ph0 + jb + 64);
            BH1c = *(const bf16x8*)(ph1 + jb + 64);
            BL0c = *(const bf16x8*)(pl0 + jb + 64);
            BL1c = *(const bf16x8*)(pl1 + jb + 64);
        }

        CHUNK(buf, 32, jb + 32, BH0n, BH1n, BL0n, BL1n);

        if (more) {
            *(float4*)&adjS[buf ^ 1][srow][scol] = aNxt;
            if (tid < 64) *(float4*)&f2S[buf ^ 1][srow & 3][scol] = fNxt;
        }
        __syncthreads();
    }

    // ---- epilogue
    float l = l_run;
    l += __shfl_xor(l, 16, 64);
    l += __shfl_xor(l, 32, 64);
    const float inv = 1.f / l;

    const float bias0 = bias[h * UU + r16];
    const float bias1 = bias[h * UU + 16 + r16];
    #pragma unroll
    for (int rg = 0; rg < 4; rg++) {
        float invr = __shfl(inv, sbase + rg, 64);
        int r = isub + sbase + rg;
        size_t orow = ((size_t)b * NN + (size_t)(i0 + r)) * FOUT;
        float o0 = c0[rg] * invr + bias0;
        o0 = o0 > 0.f ? o0 : expm1f(o0);
        out[orow + h * UU + r16] = o0;
        float o1 = c1[rg] * invr + bias1;
        o1 = o1 > 0.f ? o1 : expm1f(o1);
        out[orow + h * UU + 16 + r16] = o1;
    }
}

extern "C" void kernel_launch(void* const* d_in, const int* in_sizes, int n_in,
                              void* d_out, int out_size, void* d_ws, size_t ws_size,
                              hipStream_t stream) {
    const float* x     = (const float*)d_in[0];
    const float* adj   = (const float*)d_in[1];
    const float* W     = (const float*)d_in[2];
    const float* a_src = (const float*)d_in[3];
    const float* a_dst = (const float*)d_in[4];
    const float* bias  = (const float*)d_in[5];
    float* out = (float*)d_out;

    unsigned short* hhi = (unsigned short*)d_ws;                   // 4 MB
    unsigned short* hlo = hhi + (size_t)NB * FOUT * NN;            // 4 MB
    float* f1g = (float*)(hlo + (size_t)NB * FOUT * NN);           // 256 KB
    float* f2T = f1g + (size_t)NB * NN * NH;                       // 256 KB

    k1_feat<<<NB * NN / K1_ROWS, 256, 0, stream>>>(x, W, a_src, a_dst, hhi, hlo, f1g, f2T);
    k2_flash<<<512, 512, 0, stream>>>(adj, hhi, hlo, f1g, f2T, bias, out);
}